// Round 7
// baseline (167.125 us; speedup 1.0000x reference)
//
#include <hip/hip_runtime.h>
#include <math.h>

// Problem constants (x: (16, 1, 3, 1024, 1024) fp32)
#define W      1024            // columns
#define H      1024            // rows per batch image
#define FRAME  (1024 * 1024)   // elements per frame
#define BSTR   (3 * FRAME)     // elements per batch (3 frames)
#define ROWS   16384           // flattened rows
#define NBLK   1024            // == 4 blocks/CU x 256 CUs (capacity-resident)

typedef float v4f __attribute__((ext_vector_type(4)));

// order-preserving float <-> uint (exact atomic min/max; validated round 1)
__device__ __forceinline__ unsigned f2o(float f) {
    unsigned b = __float_as_uint(f);
    return b ^ (unsigned)(((int)b >> 31) | (int)0x80000000);
}
__device__ __forceinline__ float o2f(unsigned u) {
    unsigned mask = (u & 0x80000000u) ? 0x80000000u : 0xFFFFFFFFu;
    return __uint_as_float(u ^ mask);
}

__device__ __forceinline__ v4f min4(v4f a, v4f b) {
    v4f r; r.x = fminf(a.x,b.x); r.y = fminf(a.y,b.y); r.z = fminf(a.z,b.z); r.w = fminf(a.w,b.w); return r;
}
__device__ __forceinline__ v4f max4(v4f a, v4f b) {
    v4f r; r.x = fmaxf(a.x,b.x); r.y = fmaxf(a.y,b.y); r.z = fmaxf(a.z,b.z); r.w = fmaxf(a.w,b.w); return r;
}

// ---- reset: atomic identities + barrier counter (runs every launch, so
// poison / leftover state can never matter) ----
__global__ void reset_k(unsigned* __restrict__ mn_u, unsigned* __restrict__ mx_u,
                        unsigned* __restrict__ c1) {
    const int t = threadIdx.x;
#pragma unroll
    for (int j = 0; j < 4; ++j) {
        mn_u[t * 4 + j] = 0xFFFFFFFFu;  // +inf in monotone encoding
        mx_u[t * 4 + j] = 0u;           // -inf in monotone encoding
    }
    if (t == 0) *c1 = 0u;
}

// ---- fused: read x once, keep sout in registers, global min/max via
// device-scope atomics + counter barrier, scale + write. ----
// Block (cgp, ch): cols [cgp*256, +256), rows { ch + 256*m : m=0..63 }.
// Thread (wid, lane): rows r = ch + 256*(wid + 4j), j=0..15.
//   => batch = j, image-row = 256*wid + ch (constant per thread);
//      j==0 is the single batch-0 row (frame2-frame0), j>=1 passthrough.
__global__ __launch_bounds__(256, 4) void fused_k(const float* __restrict__ x,
                                                  unsigned* __restrict__ mn_u,
                                                  unsigned* __restrict__ mx_u,
                                                  unsigned* __restrict__ c1,
                                                  float* __restrict__ out) {
    const int cgp  = blockIdx.x & 3;    // column group, 256 cols
    const int ch   = blockIdx.x >> 2;   // 0..255
    const int lane = threadIdx.x & 63;
    const int wid  = threadIdx.x >> 6;  // 0..3
    const int col  = cgp * 256 + lane * 4;
    const int irow = 256 * wid + ch;    // image row within every batch

    const float* pb = x + ((size_t)irow << 10) + col;

    v4f s[16];
    // j = 0: batch 0, second difference frame2 - frame0
    {
        v4f f0 = *(const v4f*)pb;
        v4f f2 = *(const v4f*)(pb + 2 * FRAME);
        s[0] = f2 - f0;
    }
#pragma unroll
    for (int j = 1; j < 16; ++j)
        s[j] = *(const v4f*)(pb + (size_t)j * BSTR);

    v4f vmin = s[0], vmax = s[0];
#pragma unroll
    for (int j = 1; j < 16; ++j) { vmin = min4(vmin, s[j]); vmax = max4(vmax, s[j]); }

    // block-local 4-way reduce across waves, then 64 lanes issue atomics
    __shared__ v4f smin[4][64];
    __shared__ v4f smax[4][64];
    smin[wid][lane] = vmin;
    smax[wid][lane] = vmax;
    __syncthreads();

    if (wid == 0) {
        v4f m = min4(min4(smin[0][lane], smin[1][lane]),
                     min4(smin[2][lane], smin[3][lane]));
        v4f M = max4(max4(smax[0][lane], smax[1][lane]),
                     max4(smax[2][lane], smax[3][lane]));
        atomicMin(&mn_u[col + 0], f2o(m.x));
        atomicMin(&mn_u[col + 1], f2o(m.y));
        atomicMin(&mn_u[col + 2], f2o(m.z));
        atomicMin(&mn_u[col + 3], f2o(m.w));
        atomicMax(&mx_u[col + 0], f2o(M.x));
        atomicMax(&mx_u[col + 1], f2o(M.y));
        atomicMax(&mx_u[col + 2], f2o(M.z));
        atomicMax(&mx_u[col + 3], f2o(M.w));
        __threadfence();                 // release our atomics before c1 add
    }
    __syncthreads();

    // counter barrier: exactly NBLK co-resident blocks (grid == capacity)
    if (threadIdx.x == 0) {
        __hip_atomic_fetch_add(c1, 1u, __ATOMIC_RELEASE, __HIP_MEMORY_SCOPE_AGENT);
        while (__hip_atomic_load(c1, __ATOMIC_ACQUIRE, __HIP_MEMORY_SCOPE_AGENT) < NBLK)
            __builtin_amdgcn_s_sleep(4);
    }
    __syncthreads();

    // finalize per thread for its 4 columns (agent-scope loads: fresh values)
    float mnv[4], inv[4];
#pragma unroll
    for (int j = 0; j < 4; ++j) {
        unsigned mu = __hip_atomic_load(&mn_u[col + j], __ATOMIC_RELAXED, __HIP_MEMORY_SCOPE_AGENT);
        unsigned xu = __hip_atomic_load(&mx_u[col + j], __ATOMIC_RELAXED, __HIP_MEMORY_SCOPE_AGENT);
        float mn  = o2f(mu);
        float rng = o2f(xu) - mn;
        float den = (rng == 0.0f) ? 1.0f : rng;  // _handle_zeros_in_scale
        mnv[j] = mn;
        inv[j] = 1.0f / den;
    }
    v4f mn4; mn4.x = mnv[0]; mn4.y = mnv[1]; mn4.z = mnv[2]; mn4.w = mnv[3];
    v4f iv4; iv4.x = inv[0]; iv4.y = inv[1]; iv4.z = inv[2]; iv4.w = inv[3];

    // scale + write register-resident sout; row r = irow + 1024*j flattened
#pragma unroll
    for (int j = 0; j < 16; ++j) {
        size_t off = (((size_t)(irow + (j << 10))) << 10) + col;
        *(v4f*)(out + off) = (s[j] - mn4) * iv4;
    }
}

extern "C" void kernel_launch(void* const* d_in, const int* in_sizes, int n_in,
                              void* d_out, int out_size, void* d_ws, size_t ws_size,
                              hipStream_t stream) {
    const float* x = (const float*)d_in[0];
    float* out = (float*)d_out;

    // ws layout: mn_u[1024] | mx_u[1024] | c1
    unsigned* mn_u = (unsigned*)d_ws;
    unsigned* mx_u = mn_u + W;
    unsigned* c1   = mx_u + W;

    reset_k<<<1, 256, 0, stream>>>(mn_u, mx_u, c1);
    fused_k<<<NBLK, 256, 0, stream>>>(x, mn_u, mx_u, c1, out);
}

// Round 8
// 58.103 us; speedup vs baseline: 2.8764x; 2.8764x over previous
//
#include <hip/hip_runtime.h>
#include <math.h>

// Problem constants (x: (16, 1, 3, 1024, 1024) fp32)
#define W      1024            // columns
#define H      1024            // rows per batch image
#define FRAME  (1024 * 1024)   // elements per frame
#define BSTR   (3 * FRAME)     // elements per batch (3 frames)
#define ROWS   16384           // flattened rows

typedef float v4f __attribute__((ext_vector_type(4)));
typedef unsigned v4u __attribute__((ext_vector_type(4)));

// order-preserving float <-> uint (exact atomic min/max; validated round 1)
__device__ __forceinline__ unsigned f2o(float f) {
    unsigned b = __float_as_uint(f);
    return b ^ (unsigned)(((int)b >> 31) | (int)0x80000000);
}
__device__ __forceinline__ float o2f(unsigned u) {
    unsigned mask = (u & 0x80000000u) ? 0x80000000u : 0xFFFFFFFFu;
    return __uint_as_float(u ^ mask);
}

__device__ __forceinline__ v4f min4(v4f a, v4f b) {
    v4f r; r.x = fminf(a.x,b.x); r.y = fminf(a.y,b.y); r.z = fminf(a.z,b.z); r.w = fminf(a.w,b.w); return r;
}
__device__ __forceinline__ v4f max4(v4f a, v4f b) {
    v4f r; r.x = fmaxf(a.x,b.x); r.y = fmaxf(a.y,b.y); r.z = fmaxf(a.z,b.z); r.w = fmaxf(a.w,b.w); return r;
}

// ---- reset: atomic identities (runs every launch; ws state never matters) ----
__global__ void reset_k(unsigned* __restrict__ mn_u, unsigned* __restrict__ mx_u) {
    int i = blockIdx.x * 256 + threadIdx.x;   // 8 blocks x 256 = 2048
    if (i < W) mn_u[i] = 0xFFFFFFFFu;         // +inf (monotone encoding)
    else       mx_u[i - W] = 0u;              // -inf (monotone encoding)
}

// ---- Pass 1: per-column min/max straight into atomics (no partials).
// 1024 blocks = 4 col-groups x 256 row-groups. Thread (wid,lane) in block
// (cgp,ch): image row irow = 256*wid + ch, batches j=0..15; j==0 is the
// single batch-0 row (frame2 - frame0), j>=1 frame-0 passthrough. ----
__global__ __launch_bounds__(256) void minmax_k(const float* __restrict__ x,
                                                unsigned* __restrict__ mn_u,
                                                unsigned* __restrict__ mx_u) {
    const int cgp  = blockIdx.x & 3;    // column group, 256 cols
    const int ch   = blockIdx.x >> 2;   // 0..255
    const int lane = threadIdx.x & 63;
    const int wid  = threadIdx.x >> 6;  // 0..3
    const int col  = cgp * 256 + lane * 4;
    const int irow = 256 * wid + ch;    // image row within every batch

    const float* pb = x + ((size_t)irow << 10) + col;

    v4f vmin, vmax;
    {   // j = 0: batch 0, second difference frame2 - frame0
        v4f f0 = *(const v4f*)pb;
        v4f f2 = *(const v4f*)(pb + 2 * FRAME);
        vmin = vmax = f2 - f0;
    }
#pragma unroll
    for (int j = 1; j < 16; ++j) {
        v4f v = *(const v4f*)(pb + (size_t)j * BSTR);
        vmin = min4(vmin, v);
        vmax = max4(vmax, v);
    }

    __shared__ v4f smin[4][64];
    __shared__ v4f smax[4][64];
    smin[wid][lane] = vmin;
    smax[wid][lane] = vmax;
    __syncthreads();

    if (wid == 0) {
        v4f m = min4(min4(smin[0][lane], smin[1][lane]),
                     min4(smin[2][lane], smin[3][lane]));
        v4f M = max4(max4(smax[0][lane], smax[1][lane]),
                     max4(smax[2][lane], smax[3][lane]));
        atomicMin(&mn_u[col + 0], f2o(m.x));
        atomicMin(&mn_u[col + 1], f2o(m.y));
        atomicMin(&mn_u[col + 2], f2o(m.z));
        atomicMin(&mn_u[col + 3], f2o(m.w));
        atomicMax(&mx_u[col + 0], f2o(M.x));
        atomicMax(&mx_u[col + 1], f2o(M.y));
        atomicMax(&mx_u[col + 2], f2o(M.z));
        atomicMax(&mx_u[col + 3], f2o(M.w));
    }
}

// ---- Pass 2: one row per block (16384 blocks). Batch-0 branch is
// block-uniform; each thread owns 4 columns, decodes mn/mx from the 8 KB
// L2-resident table and scales. ----
__global__ __launch_bounds__(256) void scale_k(const float* __restrict__ x,
                                               const unsigned* __restrict__ mn_u,
                                               const unsigned* __restrict__ mx_u,
                                               float* __restrict__ out) {
    const int r   = blockIdx.x;          // flattened row 0..16383
    const int col = threadIdx.x << 2;    // 4 cols per thread
    const int b   = r >> 10;
    const int hh  = r & (H - 1);

    const float* p = x + (size_t)b * BSTR + ((size_t)hh << 10) + col;
    v4f v = *(const v4f*)p;
    if (r < H) {                         // uniform per block
        v4f f2 = *(const v4f*)(p + 2 * FRAME);
        v = f2 - v;
    }

    v4u mu = *(const v4u*)(mn_u + col);
    v4u xu = *(const v4u*)(mx_u + col);
    v4f o;
    {
        float mn = o2f(mu.x); float rng = o2f(xu.x) - mn;
        o.x = (v.x - mn) / ((rng == 0.0f) ? 1.0f : rng);
    }
    {
        float mn = o2f(mu.y); float rng = o2f(xu.y) - mn;
        o.y = (v.y - mn) / ((rng == 0.0f) ? 1.0f : rng);
    }
    {
        float mn = o2f(mu.z); float rng = o2f(xu.z) - mn;
        o.z = (v.z - mn) / ((rng == 0.0f) ? 1.0f : rng);
    }
    {
        float mn = o2f(mu.w); float rng = o2f(xu.w) - mn;
        o.w = (v.w - mn) / ((rng == 0.0f) ? 1.0f : rng);
    }
    *(v4f*)(out + ((size_t)r << 10) + col) = o;
}

extern "C" void kernel_launch(void* const* d_in, const int* in_sizes, int n_in,
                              void* d_out, int out_size, void* d_ws, size_t ws_size,
                              hipStream_t stream) {
    const float* x = (const float*)d_in[0];
    float* out = (float*)d_out;

    // ws layout: mn_u[1024] | mx_u[1024]
    unsigned* mn_u = (unsigned*)d_ws;
    unsigned* mx_u = mn_u + W;

    reset_k<<<8, 256, 0, stream>>>(mn_u, mx_u);
    minmax_k<<<1024, 256, 0, stream>>>(x, mn_u, mx_u);
    scale_k<<<16384, 256, 0, stream>>>(x, mn_u, mx_u, out);
}